// Round 1
// 285.988 us; speedup vs baseline: 1.0070x; 1.0070x over previous
//
#include <hip/hip_runtime.h>
#include <stdint.h>

typedef unsigned short u16;
typedef __attribute__((ext_vector_type(8))) short bf16x8;
typedef __attribute__((ext_vector_type(4))) float f32x4;

#define MFMA16(a, b, c) __builtin_amdgcn_mfma_f32_16x16x32_bf16((a), (b), (c), 0, 0, 0)

__device__ __forceinline__ float b2f(u16 u) {
    union { unsigned int i; float f; } v; v.i = ((unsigned int)u) << 16; return v.f;
}
__device__ __forceinline__ u16 f2b(float f) {
    union { float f; unsigned int i; } v; v.f = f;
    unsigned int r = v.i + 0x7fffu + ((v.i >> 16) & 1u);
    return (u16)(r >> 16);
}

typedef __attribute__((address_space(1))) void gvoid;
typedef __attribute__((address_space(3))) void lvoid;
__device__ __forceinline__ void gld16(const void* g, void* l) {
    __builtin_amdgcn_global_load_lds((gvoid*)(void*)g, (lvoid*)l, 16, 0, 0);
}

// Panel-swizzled block mapping: 8-row-tile panels, col-major inside a panel.
// Keeps A's reuse window ~1.6 MB -> L2-resident (FETCH 139->52 MB, measured R5).
__device__ __forceinline__ void tile_from_bid(int bid, int nTM, int nTN,
                                              int& rt, int& ct) {
    const int PW = 8;
    const int full = nTM / PW;
    const int per = PW * nTN;
    int p = bid / per;
    int pw = PW;
    int rem = bid - p * per;
    if (p >= full) { p = full; rem = bid - full * per; pw = nTM - full * PW; }
    const int c = rem / pw;
    const int r = rem - c * pw;
    rt = p * PW + r;
    ct = c;
}

// ---------------------------------------------------------------------------
// fp32 -> bf16 elementwise convert (n multiple of 4)
// ---------------------------------------------------------------------------
__global__ __launch_bounds__(256) void f32_to_bf16(const float* __restrict__ in,
                                                   u16* __restrict__ out, int n) {
    const int i = (blockIdx.x * 256 + threadIdx.x) * 4;
    if (i + 3 < n) {
        const float4 v = *(const float4*)(in + i);
        ushort4 o;
        o.x = f2b(v.x); o.y = f2b(v.y); o.z = f2b(v.z); o.w = f2b(v.w);
        *(ushort4*)(out + i) = o;
    }
}

// ---------------------------------------------------------------------------
// merged transpose + fp32->bf16 for BOTH weights (one launch):
//   blockIdx.x <  72: w_qkv (768 x 2304) -> wqkvT (2304 x 768)
//   blockIdx.x >= 72: w_proj (768 x 768) -> wprojT (768 x 768)
// ---------------------------------------------------------------------------
__global__ __launch_bounds__(256) void transpose_w(const float* __restrict__ wqkv,
                                                   const float* __restrict__ wproj,
                                                   u16* __restrict__ outQ,
                                                   u16* __restrict__ outP) {
    __shared__ float tile[32][33];
    int bx = blockIdx.x;
    const float* in; u16* out; int C;
    if (bx < 72) { in = wqkv; out = outQ; C = 2304; }
    else         { bx -= 72; in = wproj; out = outP; C = 768; }
    const int R = 768;
    const int t = threadIdx.x;
    const int r = t >> 3, c4 = (t & 7) * 4;
    const int ir = blockIdx.y * 32 + r, ic = bx * 32 + c4;
    const float4 v = *(const float4*)(in + (size_t)ir * C + ic);
    tile[r][c4 + 0] = v.x; tile[r][c4 + 1] = v.y;
    tile[r][c4 + 2] = v.z; tile[r][c4 + 3] = v.w;
    __syncthreads();
    const int orow = bx * 32 + r, ocol = blockIdx.y * 32 + c4;
    ushort4 o;
    o.x = f2b(tile[c4 + 0][r]); o.y = f2b(tile[c4 + 1][r]);
    o.z = f2b(tile[c4 + 2][r]); o.w = f2b(tile[c4 + 3][r]);
    *(ushort4*)(out + (size_t)orow * R + ocol) = o;
}

// ---------------------------------------------------------------------------
// C = A(bf16)[M x K] * Bt(bf16)[N x K]^T + bias(f32)[N]
// 128x128 tile, BK=64, 512 threads = 8 waves in 2x4 (each wave 64x32:
// acc[4][2] = 32 AGPRs). R9: software-pipelined DOUBLE-BUFFERED LDS
// (T3 "minimum 2-phase" recipe): issue tile t+1's global_load_lds into
// buf^1 BEFORE computing tile t from buf, ONE barrier per K-step (the
// compiler's vmcnt(0)-drain at the barrier now lands after the MFMAs have
// covered the load latency). K-loop unrolled x2 so buffer choice is
// compile-time (no runtime-indexed LDS base). Requires nKT even (K%128==0).
// LDS 64 KB -> 2 blocks/CU co-resident (was 4); ILP replaces TLP.
// MFMA operands swapped (D^T: l15 = row, quad*4+r = 4 cols).
// EPI: 1 = f32 store (stride N);
//      2 = fused qkv epilogue (block-uniform branch on col0):
//          Q/K tiles: bias + RoPE (intra-lane pairs) -> qkv (stride 1536);
//          V tiles: bias -> stores contiguous along l15 into VtG[bh][d][n].
// ---------------------------------------------------------------------------
template <int EPI>
__global__ __launch_bounds__(512) void gemm_bt(const u16* __restrict__ A,
                                               const u16* __restrict__ Bt,
                                               const float* __restrict__ bias,
                                               void* __restrict__ Cv,
                                               const float* __restrict__ cosp,
                                               const float* __restrict__ sinp,
                                               u16* __restrict__ VtG,
                                               int M, int N, int K) {
    __shared__ __align__(16) u16 As0[128 * 64];
    __shared__ __align__(16) u16 As1[128 * 64];
    __shared__ __align__(16) u16 Bs0[128 * 64];
    __shared__ __align__(16) u16 Bs1[128 * 64];

    const int t = threadIdx.x;
    const int lane = t & 63;
    const int wave = t >> 6;              // 0..7
    const int l15 = lane & 15, quad = lane >> 4;
    const int wm = wave >> 2;             // 0..1 (64 rows each)
    const int wn = wave & 3;              // 0..3 (32 cols each)

    int rt, ct;
    tile_from_bid(blockIdx.y * gridDim.x + blockIdx.x, gridDim.x, gridDim.y, rt, ct);
    const int row0 = rt * 128;
    const int col0 = ct * 128;

    const f32x4 fz = {0.f, 0.f, 0.f, 0.f};
    f32x4 acc[4][2];
#pragma unroll
    for (int i = 0; i < 4; ++i)
#pragma unroll
        for (int j = 0; j < 2; ++j) acc[i][j] = fz;

    // staging chunk map: chunk c -> LDS row ((c>>7)<<4)+(c&15), kc (c>>4)&7
    const u16* Ap[2];
    const u16* Bp[2];
    int off[2];
#pragma unroll
    for (int n = 0; n < 2; ++n) {
        const int c = t + n * 512;
        const int row = ((c >> 7) << 4) + (c & 15);
        const int kc = (c >> 4) & 7;
        int ar = row0 + row; if (ar > M - 1) ar = M - 1;   // clamp partial M tile
        Ap[n] = A + (size_t)ar * K + kc * 8;
        Bp[n] = Bt + (size_t)(col0 + row) * K + kc * 8;    // N % 128 == 0
        off[n] = c * 8;
    }

#define STAGE(kt_, Ad, Bd) do {                                            \
        const int kb_ = (kt_) << 6;                                        \
        gld16(Ap[0] + kb_, (Ad) + off[0]);                                 \
        gld16(Ap[1] + kb_, (Ad) + off[1]);                                 \
        gld16(Bp[0] + kb_, (Bd) + off[0]);                                 \
        gld16(Bp[1] + kb_, (Bd) + off[1]);                                 \
    } while (0)

#define COMPUTE(Asb, Bsb) do {                                             \
        _Pragma("unroll")                                                  \
        for (int kk = 0; kk < 2; ++kk) {                                   \
            bf16x8 af[4], bfr[2];                                          \
            _Pragma("unroll")                                              \
            for (int mi = 0; mi < 4; ++mi)                                 \
                af[mi] = *(const bf16x8*)((Asb) +                          \
                    ((wm * 4 + mi) * 128 + (kk * 4 + quad) * 16 + l15) * 8); \
            _Pragma("unroll")                                              \
            for (int ni = 0; ni < 2; ++ni)                                 \
                bfr[ni] = *(const bf16x8*)((Bsb) +                         \
                    ((wn * 2 + ni) * 128 + (kk * 4 + quad) * 16 + l15) * 8); \
            _Pragma("unroll")                                              \
            for (int mi = 0; mi < 4; ++mi)                                 \
                _Pragma("unroll")                                          \
                for (int ni = 0; ni < 2; ++ni)                             \
                    acc[mi][ni] = MFMA16(bfr[ni], af[mi], acc[mi][ni]);    \
        }                                                                  \
    } while (0)

    const int nKT = K >> 6;               // even (K % 128 == 0)
    STAGE(0, As0, Bs0);                   // prologue: tile 0 -> buf0
    __syncthreads();                      // (drains vmcnt0)

    for (int kt = 0; kt < nKT; kt += 2) {
        if (kt + 1 < nKT) STAGE(kt + 1, As1, Bs1);   // prefetch next -> buf1
        COMPUTE(As0, Bs0);                           // compute current (buf0)
        __syncthreads();                             // buf1 ready; buf0 released
        if (kt + 2 < nKT) STAGE(kt + 2, As0, Bs0);   // prefetch next -> buf0
        COMPUTE(As1, Bs1);                           // compute current (buf1)
        __syncthreads();                             // buf0 ready; buf1 released
    }
#undef STAGE
#undef COMPUTE

    // ---- epilogue (D^T layout: row = ...+l15, cols = colb..colb+3) ----
    if (EPI == 2) {
        if (col0 >= 1536) {
            // V tiles -> VtG[bh][d][n], stores contiguous along l15 (token n)
#pragma unroll
            for (int mi = 0; mi < 4; ++mi) {
                const int row = row0 + wm * 64 + mi * 16 + l15;
                if (row < M) {
                    const int bb = row / 577, n = row - bb * 577;
                    u16* vdst = VtG + (size_t)bb * 491520 + n;   // 12*64*640
#pragma unroll
                    for (int ni = 0; ni < 2; ++ni) {
                        const int colb = col0 + wn * 32 + ni * 16 + quad * 4;
                        const float4 bv = *(const float4*)(bias + colb);
#pragma unroll
                        for (int r = 0; r < 4; ++r) {
                            const int cv = colb + r - 1536;
                            vdst[(size_t)(cv >> 6) * 40960 + (cv & 63) * 640] =
                                f2b(acc[mi][ni][r] + ((const float*)&bv)[r]);
                        }
                    }
                }
            }
        } else {
            // Q/K tiles: bias + RoPE (intra-lane pairs) -> 1536-stride qkv
#pragma unroll
            for (int mi = 0; mi < 4; ++mi) {
                const int row = row0 + wm * 64 + mi * 16 + l15;
                if (row < M) {
                    const int bb = row / 577, n = row - bb * 577;
                    const bool hr = (n >= 1);
                    const float* cb = cosp + (size_t)(hr ? (n - 1) : 0) * 32;
                    const float* sb = sinp + (size_t)(hr ? (n - 1) : 0) * 32;
                    u16* outp = (u16*)Cv + (size_t)row * 1536;
#pragma unroll
                    for (int ni = 0; ni < 2; ++ni) {
                        const int colb = col0 + wn * 32 + ni * 16 + quad * 4;
                        const float4 bv = *(const float4*)(bias + colb);
                        const int pi = (colb & 63) >> 1;           // even
                        float2 c = *(const float2*)(cb + pi);
                        float2 s = *(const float2*)(sb + pi);
                        if (!hr) { c.x = 1.f; c.y = 1.f; s.x = 0.f; s.y = 0.f; }
                        const float v0 = acc[mi][ni][0] + bv.x;
                        const float v1 = acc[mi][ni][1] + bv.y;
                        const float v2 = acc[mi][ni][2] + bv.z;
                        const float v3 = acc[mi][ni][3] + bv.w;
                        ushort4 o;
                        o.x = f2b(v0 * c.x - v1 * s.x);
                        o.y = f2b(v0 * s.x + v1 * c.x);
                        o.z = f2b(v2 * c.y - v3 * s.y);
                        o.w = f2b(v2 * s.y + v3 * c.y);
                        *(ushort4*)(outp + colb) = o;
                    }
                }
            }
        }
    } else {
#pragma unroll
        for (int ni = 0; ni < 2; ++ni) {
            const int colb = col0 + wn * 32 + ni * 16 + quad * 4;
            const float4 bv = *(const float4*)(bias + colb);
#pragma unroll
            for (int mi = 0; mi < 4; ++mi) {
                const int row = row0 + wm * 64 + mi * 16 + l15;
                if (row < M) {
                    float4 o;
                    o.x = acc[mi][ni][0] + bv.x; o.y = acc[mi][ni][1] + bv.y;
                    o.z = acc[mi][ni][2] + bv.z; o.w = acc[mi][ni][3] + bv.w;
                    *(float4*)((float*)Cv + (size_t)row * N + colb) = o;
                }
            }
        }
    }
}

// ---------------------------------------------------------------------------
// Flash attention (unchanged from R8): block = (64-query tile, bh).
// qkv 1536-stride (Q 0..767, K 768..1535), RoPE pre-applied by gemm1;
// V in VtG[bh][d][n(640)] (tail keys masked via p=0). PSTR=72.
// ---------------------------------------------------------------------------
#define PSTR 72

__global__ __launch_bounds__(256) void attn2(const u16* __restrict__ qkv,
                                             const u16* __restrict__ VtG,
                                             u16* __restrict__ aout) {
    __shared__ __align__(16) u16 Ks[64 * 64];
    __shared__ __align__(16) u16 Vs[64 * 64];
    __shared__ __align__(16) u16 Pb[4 * 16 * PSTR];

    const int t = threadIdx.x;
    const int lane = t & 63, wave = t >> 6;
    const int l15 = lane & 15, quad = lane >> 4;
    const int qt = blockIdx.x;          // 0..9
    const int bh = blockIdx.y;          // 0..191
    const int b = bh / 12, h = bh - b * 12;
    const u16* baseQ = qkv + (size_t)b * 577 * 1536 + h * 64;
    const u16* baseK = baseQ + 768;
    const u16* vbase = VtG + (size_t)bh * 64 * 640;

    const int mq = qt * 64 + wave * 16 + l15;
    const int nq = mq < 577 ? mq : 576;
    bf16x8 aq[2];
    aq[0] = *(const bf16x8*)(baseQ + (size_t)nq * 1536 + quad * 8);
    aq[1] = *(const bf16x8*)(baseQ + (size_t)nq * 1536 + 32 + quad * 8);

    const int r15 = t & 15, cc = (t >> 4) & 7, rg0 = t >> 7;
    const int row0 = rg0 * 16 + r15, row1 = row0 + 32;
    u16* kl0 = Ks + t * 8;  u16* kl1 = Ks + (t + 256) * 8;
    u16* vl0 = Vs + t * 8;  u16* vl1 = Vs + (t + 256) * 8;
    const u16* vp0 = vbase + (size_t)row0 * 640 + cc * 8;
    const u16* vp1 = vbase + (size_t)row1 * 640 + cc * 8;

    u16* Pw = Pb + wave * 16 * PSTR;

    f32x4 oacc[4];
    const f32x4 fz = {0.f, 0.f, 0.f, 0.f};
#pragma unroll
    for (int i = 0; i < 4; ++i) oacc[i] = fz;
    float m4[4] = {-1e30f, -1e30f, -1e30f, -1e30f};
    float l4[4] = {0.f, 0.f, 0.f, 0.f};

    for (int kt = 0; kt < 10; ++kt) {
        __syncthreads();
        {
            int n0 = kt * 64 + row0; if (n0 > 576) n0 = 576;
            int n1 = kt * 64 + row1; if (n1 > 576) n1 = 576;
            gld16(baseK + (size_t)n0 * 1536 + cc * 8, kl0);
            gld16(baseK + (size_t)n1 * 1536 + cc * 8, kl1);
            gld16(vp0 + kt * 64, vl0);
            gld16(vp1 + kt * 64, vl1);
        }
        __syncthreads();

        f32x4 sacc[4];
#pragma unroll
        for (int nt = 0; nt < 4; ++nt) {
            sacc[nt] = fz;
#pragma unroll
            for (int kk = 0; kk < 2; ++kk) {
                const bf16x8 bk = *(const bf16x8*)(Ks + (nt * 128 + (kk * 4 + quad) * 16 + l15) * 8);
                sacc[nt] = MFMA16(aq[kk], bk, sacc[nt]);
            }
        }
        float sv[4][4];
#pragma unroll
        for (int nt = 0; nt < 4; ++nt) {
            const int key = kt * 64 + nt * 16 + l15;
            const bool kvalid = key < 577;
#pragma unroll
            for (int r = 0; r < 4; ++r)
                sv[nt][r] = kvalid ? sacc[nt][r] * 0.125f : -1e30f;
        }
        float mt[4];
#pragma unroll
        for (int r = 0; r < 4; ++r) {
            mt[r] = fmaxf(fmaxf(sv[0][r], sv[1][r]), fmaxf(sv[2][r], sv[3][r]));
#pragma unroll
            for (int off = 1; off <= 8; off <<= 1)
                mt[r] = fmaxf(mt[r], __shfl_xor(mt[r], off));
        }
        float alpha[4];
#pragma unroll
        for (int r = 0; r < 4; ++r) {
            const float mnew = fmaxf(m4[r], mt[r]);
            alpha[r] = __expf(m4[r] - mnew);
            m4[r] = mnew;
        }
        float lsum[4] = {0.f, 0.f, 0.f, 0.f};
#pragma unroll
        for (int nt = 0; nt < 4; ++nt) {
#pragma unroll
            for (int r = 0; r < 4; ++r) {
                const float p = __expf(sv[nt][r] - m4[r]);
                lsum[r] += p;
                Pw[(quad * 4 + r) * PSTR + nt * 16 + l15] = f2b(p);
            }
        }
#pragma unroll
        for (int r = 0; r < 4; ++r) {
#pragma unroll
            for (int off = 1; off <= 8; off <<= 1)
                lsum[r] += __shfl_xor(lsum[r], off);
            l4[r] = l4[r] * alpha[r] + lsum[r];
        }
#pragma unroll
        for (int dt = 0; dt < 4; ++dt)
#pragma unroll
            for (int r = 0; r < 4; ++r) oacc[dt][r] *= alpha[r];

        __asm__ __volatile__("s_waitcnt lgkmcnt(0)" ::: "memory");

#pragma unroll
        for (int kc = 0; kc < 2; ++kc) {
            const bf16x8 pf = *(const bf16x8*)(Pw + l15 * PSTR + kc * 32 + quad * 8);
#pragma unroll
            for (int dt = 0; dt < 4; ++dt) {
                const bf16x8 vf = *(const bf16x8*)(Vs + (dt * 128 + (kc * 4 + quad) * 16 + l15) * 8);
                oacc[dt] = MFMA16(pf, vf, oacc[dt]);
            }
        }
    }

    float linv[4];
#pragma unroll
    for (int r = 0; r < 4; ++r) linv[r] = 1.f / l4[r];
#pragma unroll
    for (int r = 0; r < 4; ++r) {
        const int n = qt * 64 + wave * 16 + quad * 4 + r;
        if (n < 577) {
            u16* op = aout + ((size_t)b * 577 + n) * 768 + h * 64 + l15;
#pragma unroll
            for (int dt = 0; dt < 4; ++dt)
                op[dt * 16] = f2b(oacc[dt][r] * linv[r]);
        }
    }
}

// ---------------------------------------------------------------------------
// Workspace layout (62,988,288 B total):
//   xb/aout @ 0        (14,180,352)  [xb dead after gemm1; aout overlaps]
//   wqkvT  @ 14,180,352 ( 3,538,944)
//   wprojT @ 17,719,296 ( 1,179,648)
//   qkv    @ 18,898,944 (28,360,704)  [Q,K only; 1536-stride; RoPE applied]
//   VtG    @ 47,259,648 (15,728,640)  [written by gemm1 epilogue]
// ---------------------------------------------------------------------------
extern "C" void kernel_launch(void* const* d_in, const int* in_sizes, int n_in,
                              void* d_out, int out_size, void* d_ws, size_t ws_size,
                              hipStream_t stream) {
    const float* x      = (const float*)d_in[0];
    const float* cosp   = (const float*)d_in[1];
    const float* sinp   = (const float*)d_in[2];
    const float* w_qkv  = (const float*)d_in[3];
    const float* b_qkv  = (const float*)d_in[4];
    const float* w_proj = (const float*)d_in[5];
    const float* b_proj = (const float*)d_in[6];
    float* out = (float*)d_out;

    char* ws = (char*)d_ws;
    u16* xb     = (u16*)(ws);
    u16* aout   = (u16*)(ws);              // overlaps xb (dead after gemm1)
    u16* wqkvT  = (u16*)(ws + 14180352);
    u16* wprojT = (u16*)(ws + 17719296);
    u16* qkv    = (u16*)(ws + 18898944);
    u16* VtG    = (u16*)(ws + 47259648);

    f32_to_bf16<<<6924, 256, 0, stream>>>(x, xb, 7090176);
    transpose_w<<<dim3(96, 24), 256, 0, stream>>>(w_qkv, w_proj, wqkvT, wprojT);
    gemm_bt<2><<<dim3(73, 18), 512, 0, stream>>>(xb, wqkvT, b_qkv, qkv,
                                                 cosp, sinp, VtG, 9232, 2304, 768);
    attn2<<<dim3(10, 192), 256, 0, stream>>>(qkv, VtG, aout);
    gemm_bt<1><<<dim3(73, 6), 512, 0, stream>>>(aout, wprojT, b_proj, out,
                                                nullptr, nullptr, nullptr, 9232, 768, 768);
}

// Round 2
// 243.394 us; speedup vs baseline: 1.1833x; 1.1750x over previous
//
#include <hip/hip_runtime.h>
#include <stdint.h>

typedef unsigned short u16;
typedef __attribute__((ext_vector_type(8))) short bf16x8;
typedef __attribute__((ext_vector_type(4))) float f32x4;

#define MFMA16(a, b, c) __builtin_amdgcn_mfma_f32_16x16x32_bf16((a), (b), (c), 0, 0, 0)

__device__ __forceinline__ float b2f(u16 u) {
    union { unsigned int i; float f; } v; v.i = ((unsigned int)u) << 16; return v.f;
}
__device__ __forceinline__ u16 f2b(float f) {
    union { float f; unsigned int i; } v; v.f = f;
    unsigned int r = v.i + 0x7fffu + ((v.i >> 16) & 1u);
    return (u16)(r >> 16);
}

typedef __attribute__((address_space(1))) void gvoid;
typedef __attribute__((address_space(3))) void lvoid;
__device__ __forceinline__ void gld16(const void* g, void* l) {
    __builtin_amdgcn_global_load_lds((gvoid*)(void*)g, (lvoid*)l, 16, 0, 0);
}

// Panel-swizzled block mapping: 8-row-tile panels, col-major inside a panel.
// Keeps A's reuse window ~1.6 MB -> L2-resident (FETCH 139->52 MB, measured R5).
__device__ __forceinline__ void tile_from_bid(int bid, int nTM, int nTN,
                                              int& rt, int& ct) {
    const int PW = 8;
    const int full = nTM / PW;
    const int per = PW * nTN;
    int p = bid / per;
    int pw = PW;
    int rem = bid - p * per;
    if (p >= full) { p = full; rem = bid - full * per; pw = nTM - full * PW; }
    const int c = rem / pw;
    const int r = rem - c * pw;
    rt = p * PW + r;
    ct = c;
}

// ---------------------------------------------------------------------------
// fp32 -> bf16 elementwise convert (n multiple of 4)
// ---------------------------------------------------------------------------
__global__ __launch_bounds__(256) void f32_to_bf16(const float* __restrict__ in,
                                                   u16* __restrict__ out, int n) {
    const int i = (blockIdx.x * 256 + threadIdx.x) * 4;
    if (i + 3 < n) {
        const float4 v = *(const float4*)(in + i);
        ushort4 o;
        o.x = f2b(v.x); o.y = f2b(v.y); o.z = f2b(v.z); o.w = f2b(v.w);
        *(ushort4*)(out + i) = o;
    }
}

// ---------------------------------------------------------------------------
// merged transpose + fp32->bf16 for BOTH weights (one launch):
//   blockIdx.x <  72: w_qkv (768 x 2304) -> wqkvT (2304 x 768)
//   blockIdx.x >= 72: w_proj (768 x 768) -> wprojT (768 x 768)
// ---------------------------------------------------------------------------
__global__ __launch_bounds__(256) void transpose_w(const float* __restrict__ wqkv,
                                                   const float* __restrict__ wproj,
                                                   u16* __restrict__ outQ,
                                                   u16* __restrict__ outP) {
    __shared__ float tile[32][33];
    int bx = blockIdx.x;
    const float* in; u16* out; int C;
    if (bx < 72) { in = wqkv; out = outQ; C = 2304; }
    else         { bx -= 72; in = wproj; out = outP; C = 768; }
    const int R = 768;
    const int t = threadIdx.x;
    const int r = t >> 3, c4 = (t & 7) * 4;
    const int ir = blockIdx.y * 32 + r, ic = bx * 32 + c4;
    const float4 v = *(const float4*)(in + (size_t)ir * C + ic);
    tile[r][c4 + 0] = v.x; tile[r][c4 + 1] = v.y;
    tile[r][c4 + 2] = v.z; tile[r][c4 + 3] = v.w;
    __syncthreads();
    const int orow = bx * 32 + r, ocol = blockIdx.y * 32 + c4;
    ushort4 o;
    o.x = f2b(tile[c4 + 0][r]); o.y = f2b(tile[c4 + 1][r]);
    o.z = f2b(tile[c4 + 2][r]); o.w = f2b(tile[c4 + 3][r]);
    *(ushort4*)(out + (size_t)orow * R + ocol) = o;
}

// ---------------------------------------------------------------------------
// C = A(bf16)[M x K] * Bt(bf16)[N x K]^T + bias(f32)[N]
// 128x128 tile, BK=64, 512 threads = 8 waves in 2x4 (each wave 64x32:
// acc[4][2] = 32 AGPRs). Double-buffered LDS, one barrier per K-step.
//
// R10: COALESCED STAGING. Old map: per wave-instr 16 rows x 64B = 16
// half-line transactions (R9's zero-delta proved the kernel is VMEM-
// transaction-bound, not barrier-bound). New map: chunk g (0..1023) ->
// row g>>3, slot g&7; one wave covers 8 consecutive rows x 128B fully =
// 8 full-line transactions (2x fewer, 2x fatter). LDS becomes row-major
// [128][64] u16 -> 32-way read conflict, fixed per rule #21 by the XOR
// involution on BOTH sides: global source slot = (g&7) ^ (row&7) (LDS
// dest stays linear as global_load_lds requires), ds_read k-granule =
// (kk*4+quad) ^ (l15&7). Bank aliasing after swizzle: 2-way = free (m136).
// Fragment per lane is bit-identical to R9 (row (..)*16+l15, k-chunk
// (kk*4+quad)*8) -> math unchanged.
//
// MFMA operands swapped (D^T: l15 = row, quad*4+r = 4 cols).
// EPI: 1 = f32 store (stride N);
//      2 = fused qkv epilogue (block-uniform branch on col0):
//          Q/K tiles: bias + RoPE (intra-lane pairs) -> qkv (stride 1536);
//          V tiles: bias -> stores contiguous along l15 into VtG[bh][d][n].
// ---------------------------------------------------------------------------
template <int EPI>
__global__ __launch_bounds__(512) void gemm_bt(const u16* __restrict__ A,
                                               const u16* __restrict__ Bt,
                                               const float* __restrict__ bias,
                                               void* __restrict__ Cv,
                                               const float* __restrict__ cosp,
                                               const float* __restrict__ sinp,
                                               u16* __restrict__ VtG,
                                               int M, int N, int K) {
    __shared__ __align__(16) u16 As0[128 * 64];
    __shared__ __align__(16) u16 As1[128 * 64];
    __shared__ __align__(16) u16 Bs0[128 * 64];
    __shared__ __align__(16) u16 Bs1[128 * 64];

    const int t = threadIdx.x;
    const int lane = t & 63;
    const int wave = t >> 6;              // 0..7
    const int l15 = lane & 15, quad = lane >> 4;
    const int wm = wave >> 2;             // 0..1 (64 rows each)
    const int wn = wave & 3;              // 0..3 (32 cols each)

    int rt, ct;
    tile_from_bid(blockIdx.y * gridDim.x + blockIdx.x, gridDim.x, gridDim.y, rt, ct);
    const int row0 = rt * 128;
    const int col0 = ct * 128;

    const f32x4 fz = {0.f, 0.f, 0.f, 0.f};
    f32x4 acc[4][2];
#pragma unroll
    for (int i = 0; i < 4; ++i)
#pragma unroll
        for (int j = 0; j < 2; ++j) acc[i][j] = fz;

    // Coalesced staging map: chunk g -> row g>>3, LDS slot g&7,
    // global slot (g&7)^(row&7) (XOR source pre-swizzle; involution).
    const u16* Ap[2];
    const u16* Bp[2];
    int off[2];
#pragma unroll
    for (int n = 0; n < 2; ++n) {
        const int g = t + n * 512;
        const int row = g >> 3;
        const int slot = (g & 7) ^ (row & 7);
        int ar = row0 + row; if (ar > M - 1) ar = M - 1;   // clamp partial M tile
        Ap[n] = A + (size_t)ar * K + slot * 8;
        Bp[n] = Bt + (size_t)(col0 + row) * K + slot * 8;  // N % 128 == 0
        off[n] = g * 8;                                    // u16 units (linear LDS)
    }

#define STAGE(kt_, Ad, Bd) do {                                            \
        const int kb_ = (kt_) << 6;                                        \
        gld16(Ap[0] + kb_, (Ad) + off[0]);                                 \
        gld16(Ap[1] + kb_, (Ad) + off[1]);                                 \
        gld16(Bp[0] + kb_, (Bd) + off[0]);                                 \
        gld16(Bp[1] + kb_, (Bd) + off[1]);                                 \
    } while (0)

    // Row-major [row][64] LDS; k-granule XOR-swizzled by l15&7.
#define COMPUTE(Asb, Bsb) do {                                             \
        _Pragma("unroll")                                                  \
        for (int kk = 0; kk < 2; ++kk) {                                   \
            const int swk = ((kk * 4 + quad) ^ (l15 & 7)) * 8;             \
            bf16x8 af[4], bfr[2];                                          \
            _Pragma("unroll")                                              \
            for (int mi = 0; mi < 4; ++mi)                                 \
                af[mi] = *(const bf16x8*)((Asb) +                          \
                    ((wm * 4 + mi) * 16 + l15) * 64 + swk);                \
            _Pragma("unroll")                                              \
            for (int ni = 0; ni < 2; ++ni)                                 \
                bfr[ni] = *(const bf16x8*)((Bsb) +                         \
                    ((wn * 2 + ni) * 16 + l15) * 64 + swk);                \
            _Pragma("unroll")                                              \
            for (int mi = 0; mi < 4; ++mi)                                 \
                _Pragma("unroll")                                          \
                for (int ni = 0; ni < 2; ++ni)                             \
                    acc[mi][ni] = MFMA16(bfr[ni], af[mi], acc[mi][ni]);    \
        }                                                                  \
    } while (0)

    const int nKT = K >> 6;               // even (K % 128 == 0)
    STAGE(0, As0, Bs0);                   // prologue: tile 0 -> buf0
    __syncthreads();                      // (drains vmcnt0)

    for (int kt = 0; kt < nKT; kt += 2) {
        if (kt + 1 < nKT) STAGE(kt + 1, As1, Bs1);   // prefetch next -> buf1
        COMPUTE(As0, Bs0);                           // compute current (buf0)
        __syncthreads();                             // buf1 ready; buf0 released
        if (kt + 2 < nKT) STAGE(kt + 2, As0, Bs0);   // prefetch next -> buf0
        COMPUTE(As1, Bs1);                           // compute current (buf1)
        __syncthreads();                             // buf0 ready; buf1 released
    }
#undef STAGE
#undef COMPUTE

    // ---- epilogue (D^T layout: row = ...+l15, cols = colb..colb+3) ----
    if (EPI == 2) {
        if (col0 >= 1536) {
            // V tiles -> VtG[bh][d][n], stores contiguous along l15 (token n)
#pragma unroll
            for (int mi = 0; mi < 4; ++mi) {
                const int row = row0 + wm * 64 + mi * 16 + l15;
                if (row < M) {
                    const int bb = row / 577, n = row - bb * 577;
                    u16* vdst = VtG + (size_t)bb * 491520 + n;   // 12*64*640
#pragma unroll
                    for (int ni = 0; ni < 2; ++ni) {
                        const int colb = col0 + wn * 32 + ni * 16 + quad * 4;
                        const float4 bv = *(const float4*)(bias + colb);
#pragma unroll
                        for (int r = 0; r < 4; ++r) {
                            const int cv = colb + r - 1536;
                            vdst[(size_t)(cv >> 6) * 40960 + (cv & 63) * 640] =
                                f2b(acc[mi][ni][r] + ((const float*)&bv)[r]);
                        }
                    }
                }
            }
        } else {
            // Q/K tiles: bias + RoPE (intra-lane pairs) -> 1536-stride qkv
#pragma unroll
            for (int mi = 0; mi < 4; ++mi) {
                const int row = row0 + wm * 64 + mi * 16 + l15;
                if (row < M) {
                    const int bb = row / 577, n = row - bb * 577;
                    const bool hr = (n >= 1);
                    const float* cb = cosp + (size_t)(hr ? (n - 1) : 0) * 32;
                    const float* sb = sinp + (size_t)(hr ? (n - 1) : 0) * 32;
                    u16* outp = (u16*)Cv + (size_t)row * 1536;
#pragma unroll
                    for (int ni = 0; ni < 2; ++ni) {
                        const int colb = col0 + wn * 32 + ni * 16 + quad * 4;
                        const float4 bv = *(const float4*)(bias + colb);
                        const int pi = (colb & 63) >> 1;           // even
                        float2 c = *(const float2*)(cb + pi);
                        float2 s = *(const float2*)(sb + pi);
                        if (!hr) { c.x = 1.f; c.y = 1.f; s.x = 0.f; s.y = 0.f; }
                        const float v0 = acc[mi][ni][0] + bv.x;
                        const float v1 = acc[mi][ni][1] + bv.y;
                        const float v2 = acc[mi][ni][2] + bv.z;
                        const float v3 = acc[mi][ni][3] + bv.w;
                        ushort4 o;
                        o.x = f2b(v0 * c.x - v1 * s.x);
                        o.y = f2b(v0 * s.x + v1 * c.x);
                        o.z = f2b(v2 * c.y - v3 * s.y);
                        o.w = f2b(v2 * s.y + v3 * c.y);
                        *(ushort4*)(outp + colb) = o;
                    }
                }
            }
        }
    } else {
#pragma unroll
        for (int ni = 0; ni < 2; ++ni) {
            const int colb = col0 + wn * 32 + ni * 16 + quad * 4;
            const float4 bv = *(const float4*)(bias + colb);
#pragma unroll
            for (int mi = 0; mi < 4; ++mi) {
                const int row = row0 + wm * 64 + mi * 16 + l15;
                if (row < M) {
                    float4 o;
                    o.x = acc[mi][ni][0] + bv.x; o.y = acc[mi][ni][1] + bv.y;
                    o.z = acc[mi][ni][2] + bv.z; o.w = acc[mi][ni][3] + bv.w;
                    *(float4*)((float*)Cv + (size_t)row * N + colb) = o;
                }
            }
        }
    }
}

// ---------------------------------------------------------------------------
// Flash attention (unchanged from R8): block = (64-query tile, bh).
// qkv 1536-stride (Q 0..767, K 768..1535), RoPE pre-applied by gemm1;
// V in VtG[bh][d][n(640)] (tail keys masked via p=0). PSTR=72.
// ---------------------------------------------------------------------------
#define PSTR 72

__global__ __launch_bounds__(256) void attn2(const u16* __restrict__ qkv,
                                             const u16* __restrict__ VtG,
                                             u16* __restrict__ aout) {
    __shared__ __align__(16) u16 Ks[64 * 64];
    __shared__ __align__(16) u16 Vs[64 * 64];
    __shared__ __align__(16) u16 Pb[4 * 16 * PSTR];

    const int t = threadIdx.x;
    const int lane = t & 63, wave = t >> 6;
    const int l15 = lane & 15, quad = lane >> 4;
    const int qt = blockIdx.x;          // 0..9
    const int bh = blockIdx.y;          // 0..191
    const int b = bh / 12, h = bh - b * 12;
    const u16* baseQ = qkv + (size_t)b * 577 * 1536 + h * 64;
    const u16* baseK = baseQ + 768;
    const u16* vbase = VtG + (size_t)bh * 64 * 640;

    const int mq = qt * 64 + wave * 16 + l15;
    const int nq = mq < 577 ? mq : 576;
    bf16x8 aq[2];
    aq[0] = *(const bf16x8*)(baseQ + (size_t)nq * 1536 + quad * 8);
    aq[1] = *(const bf16x8*)(baseQ + (size_t)nq * 1536 + 32 + quad * 8);

    const int r15 = t & 15, cc = (t >> 4) & 7, rg0 = t >> 7;
    const int row0 = rg0 * 16 + r15, row1 = row0 + 32;
    u16* kl0 = Ks + t * 8;  u16* kl1 = Ks + (t + 256) * 8;
    u16* vl0 = Vs + t * 8;  u16* vl1 = Vs + (t + 256) * 8;
    const u16* vp0 = vbase + (size_t)row0 * 640 + cc * 8;
    const u16* vp1 = vbase + (size_t)row1 * 640 + cc * 8;

    u16* Pw = Pb + wave * 16 * PSTR;

    f32x4 oacc[4];
    const f32x4 fz = {0.f, 0.f, 0.f, 0.f};
#pragma unroll
    for (int i = 0; i < 4; ++i) oacc[i] = fz;
    float m4[4] = {-1e30f, -1e30f, -1e30f, -1e30f};
    float l4[4] = {0.f, 0.f, 0.f, 0.f};

    for (int kt = 0; kt < 10; ++kt) {
        __syncthreads();
        {
            int n0 = kt * 64 + row0; if (n0 > 576) n0 = 576;
            int n1 = kt * 64 + row1; if (n1 > 576) n1 = 576;
            gld16(baseK + (size_t)n0 * 1536 + cc * 8, kl0);
            gld16(baseK + (size_t)n1 * 1536 + cc * 8, kl1);
            gld16(vp0 + kt * 64, vl0);
            gld16(vp1 + kt * 64, vl1);
        }
        __syncthreads();

        f32x4 sacc[4];
#pragma unroll
        for (int nt = 0; nt < 4; ++nt) {
            sacc[nt] = fz;
#pragma unroll
            for (int kk = 0; kk < 2; ++kk) {
                const bf16x8 bk = *(const bf16x8*)(Ks + (nt * 128 + (kk * 4 + quad) * 16 + l15) * 8);
                sacc[nt] = MFMA16(aq[kk], bk, sacc[nt]);
            }
        }
        float sv[4][4];
#pragma unroll
        for (int nt = 0; nt < 4; ++nt) {
            const int key = kt * 64 + nt * 16 + l15;
            const bool kvalid = key < 577;
#pragma unroll
            for (int r = 0; r < 4; ++r)
                sv[nt][r] = kvalid ? sacc[nt][r] * 0.125f : -1e30f;
        }
        float mt[4];
#pragma unroll
        for (int r = 0; r < 4; ++r) {
            mt[r] = fmaxf(fmaxf(sv[0][r], sv[1][r]), fmaxf(sv[2][r], sv[3][r]));
#pragma unroll
            for (int off = 1; off <= 8; off <<= 1)
                mt[r] = fmaxf(mt[r], __shfl_xor(mt[r], off));
        }
        float alpha[4];
#pragma unroll
        for (int r = 0; r < 4; ++r) {
            const float mnew = fmaxf(m4[r], mt[r]);
            alpha[r] = __expf(m4[r] - mnew);
            m4[r] = mnew;
        }
        float lsum[4] = {0.f, 0.f, 0.f, 0.f};
#pragma unroll
        for (int nt = 0; nt < 4; ++nt) {
#pragma unroll
            for (int r = 0; r < 4; ++r) {
                const float p = __expf(sv[nt][r] - m4[r]);
                lsum[r] += p;
                Pw[(quad * 4 + r) * PSTR + nt * 16 + l15] = f2b(p);
            }
        }
#pragma unroll
        for (int r = 0; r < 4; ++r) {
#pragma unroll
            for (int off = 1; off <= 8; off <<= 1)
                lsum[r] += __shfl_xor(lsum[r], off);
            l4[r] = l4[r] * alpha[r] + lsum[r];
        }
#pragma unroll
        for (int dt = 0; dt < 4; ++dt)
#pragma unroll
            for (int r = 0; r < 4; ++r) oacc[dt][r] *= alpha[r];

        __asm__ __volatile__("s_waitcnt lgkmcnt(0)" ::: "memory");

#pragma unroll
        for (int kc = 0; kc < 2; ++kc) {
            const bf16x8 pf = *(const bf16x8*)(Pw + l15 * PSTR + kc * 32 + quad * 8);
#pragma unroll
            for (int dt = 0; dt < 4; ++dt) {
                const bf16x8 vf = *(const bf16x8*)(Vs + (dt * 128 + (kc * 4 + quad) * 16 + l15) * 8);
                oacc[dt] = MFMA16(pf, vf, oacc[dt]);
            }
        }
    }

    float linv[4];
#pragma unroll
    for (int r = 0; r < 4; ++r) linv[r] = 1.f / l4[r];
#pragma unroll
    for (int r = 0; r < 4; ++r) {
        const int n = qt * 64 + wave * 16 + quad * 4 + r;
        if (n < 577) {
            u16* op = aout + ((size_t)b * 577 + n) * 768 + h * 64 + l15;
#pragma unroll
            for (int dt = 0; dt < 4; ++dt)
                op[dt * 16] = f2b(oacc[dt][r] * linv[r]);
        }
    }
}

// ---------------------------------------------------------------------------
// Workspace layout (62,988,288 B total):
//   xb/aout @ 0        (14,180,352)  [xb dead after gemm1; aout overlaps]
//   wqkvT  @ 14,180,352 ( 3,538,944)
//   wprojT @ 17,719,296 ( 1,179,648)
//   qkv    @ 18,898,944 (28,360,704)  [Q,K only; 1536-stride; RoPE applied]
//   VtG    @ 47,259,648 (15,728,640)  [written by gemm1 epilogue]
// ---------------------------------------------------------------------------
extern "C" void kernel_launch(void* const* d_in, const int* in_sizes, int n_in,
                              void* d_out, int out_size, void* d_ws, size_t ws_size,
                              hipStream_t stream) {
    const float* x      = (const float*)d_in[0];
    const float* cosp   = (const float*)d_in[1];
    const float* sinp   = (const float*)d_in[2];
    const float* w_qkv  = (const float*)d_in[3];
    const float* b_qkv  = (const float*)d_in[4];
    const float* w_proj = (const float*)d_in[5];
    const float* b_proj = (const float*)d_in[6];
    float* out = (float*)d_out;

    char* ws = (char*)d_ws;
    u16* xb     = (u16*)(ws);
    u16* aout   = (u16*)(ws);              // overlaps xb (dead after gemm1)
    u16* wqkvT  = (u16*)(ws + 14180352);
    u16* wprojT = (u16*)(ws + 17719296);
    u16* qkv    = (u16*)(ws + 18898944);
    u16* VtG    = (u16*)(ws + 47259648);

    f32_to_bf16<<<6924, 256, 0, stream>>>(x, xb, 7090176);
    transpose_w<<<dim3(96, 24), 256, 0, stream>>>(w_qkv, w_proj, wqkvT, wprojT);
    gemm_bt<2><<<dim3(73, 18), 512, 0, stream>>>(xb, wqkvT, b_qkv, qkv,
                                                 cosp, sinp, VtG, 9232, 2304, 768);
    attn2<<<dim3(10, 192), 256, 0, stream>>>(qkv, VtG, aout);
    gemm_bt<1><<<dim3(73, 6), 512, 0, stream>>>(aout, wprojT, b_proj, out,
                                                nullptr, nullptr, nullptr, 9232, 768, 768);
}

// Round 3
// 229.581 us; speedup vs baseline: 1.2544x; 1.0602x over previous
//
#include <hip/hip_runtime.h>
#include <stdint.h>

typedef unsigned short u16;
typedef __attribute__((ext_vector_type(8))) short bf16x8;
typedef __attribute__((ext_vector_type(4))) float f32x4;

#define MFMA16(a, b, c) __builtin_amdgcn_mfma_f32_16x16x32_bf16((a), (b), (c), 0, 0, 0)

__device__ __forceinline__ float b2f(u16 u) {
    union { unsigned int i; float f; } v; v.i = ((unsigned int)u) << 16; return v.f;
}
__device__ __forceinline__ u16 f2b(float f) {
    union { float f; unsigned int i; } v; v.f = f;
    unsigned int r = v.i + 0x7fffu + ((v.i >> 16) & 1u);
    return (u16)(r >> 16);
}
// native 2^x (v_exp_f32); schedulable asm, no memory clobber
__device__ __forceinline__ float exp2_fast(float x) {
    float r; __asm__("v_exp_f32 %0, %1" : "=v"(r) : "v"(x)); return r;
}

typedef __attribute__((address_space(1))) void gvoid;
typedef __attribute__((address_space(3))) void lvoid;
__device__ __forceinline__ void gld16(const void* g, void* l) {
    __builtin_amdgcn_global_load_lds((gvoid*)(void*)g, (lvoid*)l, 16, 0, 0);
}

// Panel-swizzled block mapping: 8-row-tile panels, col-major inside a panel.
// Keeps A's reuse window ~1.6 MB -> L2-resident (FETCH 139->52 MB, measured R5).
__device__ __forceinline__ void tile_from_bid(int bid, int nTM, int nTN,
                                              int& rt, int& ct) {
    const int PW = 8;
    const int full = nTM / PW;
    const int per = PW * nTN;
    int p = bid / per;
    int pw = PW;
    int rem = bid - p * per;
    if (p >= full) { p = full; rem = bid - full * per; pw = nTM - full * PW; }
    const int c = rem / pw;
    const int r = rem - c * pw;
    rt = p * PW + r;
    ct = c;
}

// ---------------------------------------------------------------------------
// fp32 -> bf16 elementwise convert (n multiple of 4)
// ---------------------------------------------------------------------------
__global__ __launch_bounds__(256) void f32_to_bf16(const float* __restrict__ in,
                                                   u16* __restrict__ out, int n) {
    const int i = (blockIdx.x * 256 + threadIdx.x) * 4;
    if (i + 3 < n) {
        const float4 v = *(const float4*)(in + i);
        ushort4 o;
        o.x = f2b(v.x); o.y = f2b(v.y); o.z = f2b(v.z); o.w = f2b(v.w);
        *(ushort4*)(out + i) = o;
    }
}

// ---------------------------------------------------------------------------
// merged transpose + fp32->bf16 for BOTH weights (one launch):
//   blockIdx.x <  72: w_qkv (768 x 2304) -> wqkvT (2304 x 768)
//   blockIdx.x >= 72: w_proj (768 x 768) -> wprojT (768 x 768)
// ---------------------------------------------------------------------------
__global__ __launch_bounds__(256) void transpose_w(const float* __restrict__ wqkv,
                                                   const float* __restrict__ wproj,
                                                   u16* __restrict__ outQ,
                                                   u16* __restrict__ outP) {
    __shared__ float tile[32][33];
    int bx = blockIdx.x;
    const float* in; u16* out; int C;
    if (bx < 72) { in = wqkv; out = outQ; C = 2304; }
    else         { bx -= 72; in = wproj; out = outP; C = 768; }
    const int R = 768;
    const int t = threadIdx.x;
    const int r = t >> 3, c4 = (t & 7) * 4;
    const int ir = blockIdx.y * 32 + r, ic = bx * 32 + c4;
    const float4 v = *(const float4*)(in + (size_t)ir * C + ic);
    tile[r][c4 + 0] = v.x; tile[r][c4 + 1] = v.y;
    tile[r][c4 + 2] = v.z; tile[r][c4 + 3] = v.w;
    __syncthreads();
    const int orow = bx * 32 + r, ocol = blockIdx.y * 32 + c4;
    ushort4 o;
    o.x = f2b(tile[c4 + 0][r]); o.y = f2b(tile[c4 + 1][r]);
    o.z = f2b(tile[c4 + 2][r]); o.w = f2b(tile[c4 + 3][r]);
    *(ushort4*)(out + (size_t)orow * R + ocol) = o;
}

// ---------------------------------------------------------------------------
// C = A(bf16)[M x K] * Bt(bf16)[N x K]^T + bias(f32)[N]
// 128x128 tile, BK=64, 512 threads = 8 waves in 2x4 (each wave 64x32:
// acc[4][2] = 32 AGPRs). Double-buffered LDS, one barrier per K-step.
// R10 (kept, verified): coalesced staging (8 rows x 128B full lines per
// wave-instr) + XOR involution on both sides; SQ_LDS_BANK_CONFLICT == 0.
// MFMA operands swapped (D^T: l15 = row, quad*4+r = 4 cols).
// EPI: 1 = f32 store (stride N);
//      2 = fused qkv epilogue (block-uniform branch on col0):
//          Q/K tiles: bias + RoPE (intra-lane pairs) -> qkv (stride 1536);
//          V tiles: bias -> stores contiguous along l15 into VtG[bh][d][n].
// ---------------------------------------------------------------------------
template <int EPI>
__global__ __launch_bounds__(512) void gemm_bt(const u16* __restrict__ A,
                                               const u16* __restrict__ Bt,
                                               const float* __restrict__ bias,
                                               void* __restrict__ Cv,
                                               const float* __restrict__ cosp,
                                               const float* __restrict__ sinp,
                                               u16* __restrict__ VtG,
                                               int M, int N, int K) {
    __shared__ __align__(16) u16 As0[128 * 64];
    __shared__ __align__(16) u16 As1[128 * 64];
    __shared__ __align__(16) u16 Bs0[128 * 64];
    __shared__ __align__(16) u16 Bs1[128 * 64];

    const int t = threadIdx.x;
    const int lane = t & 63;
    const int wave = t >> 6;              // 0..7
    const int l15 = lane & 15, quad = lane >> 4;
    const int wm = wave >> 2;             // 0..1 (64 rows each)
    const int wn = wave & 3;              // 0..3 (32 cols each)

    int rt, ct;
    tile_from_bid(blockIdx.y * gridDim.x + blockIdx.x, gridDim.x, gridDim.y, rt, ct);
    const int row0 = rt * 128;
    const int col0 = ct * 128;

    const f32x4 fz = {0.f, 0.f, 0.f, 0.f};
    f32x4 acc[4][2];
#pragma unroll
    for (int i = 0; i < 4; ++i)
#pragma unroll
        for (int j = 0; j < 2; ++j) acc[i][j] = fz;

    // Coalesced staging map: chunk g -> row g>>3, LDS slot g&7,
    // global slot (g&7)^(row&7) (XOR source pre-swizzle; involution).
    const u16* Ap[2];
    const u16* Bp[2];
    int off[2];
#pragma unroll
    for (int n = 0; n < 2; ++n) {
        const int g = t + n * 512;
        const int row = g >> 3;
        const int slot = (g & 7) ^ (row & 7);
        int ar = row0 + row; if (ar > M - 1) ar = M - 1;   // clamp partial M tile
        Ap[n] = A + (size_t)ar * K + slot * 8;
        Bp[n] = Bt + (size_t)(col0 + row) * K + slot * 8;  // N % 128 == 0
        off[n] = g * 8;                                    // u16 units (linear LDS)
    }

#define STAGE(kt_, Ad, Bd) do {                                            \
        const int kb_ = (kt_) << 6;                                        \
        gld16(Ap[0] + kb_, (Ad) + off[0]);                                 \
        gld16(Ap[1] + kb_, (Ad) + off[1]);                                 \
        gld16(Bp[0] + kb_, (Bd) + off[0]);                                 \
        gld16(Bp[1] + kb_, (Bd) + off[1]);                                 \
    } while (0)

    // Row-major [row][64] LDS; k-granule XOR-swizzled by l15&7.
#define COMPUTE(Asb, Bsb) do {                                             \
        _Pragma("unroll")                                                  \
        for (int kk = 0; kk < 2; ++kk) {                                   \
            const int swk = ((kk * 4 + quad) ^ (l15 & 7)) * 8;             \
            bf16x8 af[4], bfr[2];                                          \
            _Pragma("unroll")                                              \
            for (int mi = 0; mi < 4; ++mi)                                 \
                af[mi] = *(const bf16x8*)((Asb) +                          \
                    ((wm * 4 + mi) * 16 + l15) * 64 + swk);                \
            _Pragma("unroll")                                              \
            for (int ni = 0; ni < 2; ++ni)                                 \
                bfr[ni] = *(const bf16x8*)((Bsb) +                         \
                    ((wn * 2 + ni) * 16 + l15) * 64 + swk);                \
            _Pragma("unroll")                                              \
            for (int mi = 0; mi < 4; ++mi)                                 \
                _Pragma("unroll")                                          \
                for (int ni = 0; ni < 2; ++ni)                             \
                    acc[mi][ni] = MFMA16(bfr[ni], af[mi], acc[mi][ni]);    \
        }                                                                  \
    } while (0)

    const int nKT = K >> 6;               // even (K % 128 == 0)
    STAGE(0, As0, Bs0);                   // prologue: tile 0 -> buf0
    __syncthreads();                      // (drains vmcnt0)

    for (int kt = 0; kt < nKT; kt += 2) {
        if (kt + 1 < nKT) STAGE(kt + 1, As1, Bs1);   // prefetch next -> buf1
        COMPUTE(As0, Bs0);                           // compute current (buf0)
        __syncthreads();                             // buf1 ready; buf0 released
        if (kt + 2 < nKT) STAGE(kt + 2, As0, Bs0);   // prefetch next -> buf0
        COMPUTE(As1, Bs1);                           // compute current (buf1)
        __syncthreads();                             // buf0 ready; buf1 released
    }
#undef STAGE
#undef COMPUTE

    // ---- epilogue (D^T layout: row = ...+l15, cols = colb..colb+3) ----
    if (EPI == 2) {
        if (col0 >= 1536) {
            // V tiles -> VtG[bh][d][n], stores contiguous along l15 (token n)
#pragma unroll
            for (int mi = 0; mi < 4; ++mi) {
                const int row = row0 + wm * 64 + mi * 16 + l15;
                if (row < M) {
                    const int bb = row / 577, n = row - bb * 577;
                    u16* vdst = VtG + (size_t)bb * 491520 + n;   // 12*64*640
#pragma unroll
                    for (int ni = 0; ni < 2; ++ni) {
                        const int colb = col0 + wn * 32 + ni * 16 + quad * 4;
                        const float4 bv = *(const float4*)(bias + colb);
#pragma unroll
                        for (int r = 0; r < 4; ++r) {
                            const int cv = colb + r - 1536;
                            vdst[(size_t)(cv >> 6) * 40960 + (cv & 63) * 640] =
                                f2b(acc[mi][ni][r] + ((const float*)&bv)[r]);
                        }
                    }
                }
            }
        } else {
            // Q/K tiles: bias + RoPE (intra-lane pairs) -> 1536-stride qkv
#pragma unroll
            for (int mi = 0; mi < 4; ++mi) {
                const int row = row0 + wm * 64 + mi * 16 + l15;
                if (row < M) {
                    const int bb = row / 577, n = row - bb * 577;
                    const bool hr = (n >= 1);
                    const float* cb = cosp + (size_t)(hr ? (n - 1) : 0) * 32;
                    const float* sb = sinp + (size_t)(hr ? (n - 1) : 0) * 32;
                    u16* outp = (u16*)Cv + (size_t)row * 1536;
#pragma unroll
                    for (int ni = 0; ni < 2; ++ni) {
                        const int colb = col0 + wn * 32 + ni * 16 + quad * 4;
                        const float4 bv = *(const float4*)(bias + colb);
                        const int pi = (colb & 63) >> 1;           // even
                        float2 c = *(const float2*)(cb + pi);
                        float2 s = *(const float2*)(sb + pi);
                        if (!hr) { c.x = 1.f; c.y = 1.f; s.x = 0.f; s.y = 0.f; }
                        const float v0 = acc[mi][ni][0] + bv.x;
                        const float v1 = acc[mi][ni][1] + bv.y;
                        const float v2 = acc[mi][ni][2] + bv.z;
                        const float v3 = acc[mi][ni][3] + bv.w;
                        ushort4 o;
                        o.x = f2b(v0 * c.x - v1 * s.x);
                        o.y = f2b(v0 * s.x + v1 * c.x);
                        o.z = f2b(v2 * c.y - v3 * s.y);
                        o.w = f2b(v2 * s.y + v3 * c.y);
                        *(ushort4*)(outp + colb) = o;
                    }
                }
            }
        }
    } else {
#pragma unroll
        for (int ni = 0; ni < 2; ++ni) {
            const int colb = col0 + wn * 32 + ni * 16 + quad * 4;
            const float4 bv = *(const float4*)(bias + colb);
#pragma unroll
            for (int mi = 0; mi < 4; ++mi) {
                const int row = row0 + wm * 64 + mi * 16 + l15;
                if (row < M) {
                    float4 o;
                    o.x = acc[mi][ni][0] + bv.x; o.y = acc[mi][ni][1] + bv.y;
                    o.z = acc[mi][ni][2] + bv.z; o.w = acc[mi][ni][3] + bv.w;
                    *(float4*)((float*)Cv + (size_t)row * N + colb) = o;
                }
            }
        }
    }
}

// ---------------------------------------------------------------------------
// Flash attention R11: block = (64-query tile, bh), 1D grid with bijective
// XCD-chunked swizzle (same-bh q-tiles colocate on one XCD's L2: K/V 147KB
// reused instead of re-fetched per XCD; FETCH was 124MB vs ~46MB ideal).
// Coalesced XOR-swizzled K/V staging (8 rows x 128B full lines, proven
// 0-conflict in gemm_bt) + double-buffered prefetch pipeline (one barrier
// per K-tile, vmcnt drain lands after softmax+PV covers latency).
// Raw-score base-2 softmax: p = exp2(fma(s, C, -m*C)), C = 0.125*log2e;
// key-masking only in the kt=9 tail (kt<=8 tiles are all-valid).
// ---------------------------------------------------------------------------
#define PSTR 72
#define CEXP 0.18033688011112042f   /* 0.125 * log2(e) */

__global__ __launch_bounds__(256) void attn2(const u16* __restrict__ qkv,
                                             const u16* __restrict__ VtG,
                                             u16* __restrict__ aout) {
    __shared__ __align__(16) u16 Ks0[64 * 64];
    __shared__ __align__(16) u16 Ks1[64 * 64];
    __shared__ __align__(16) u16 Vs0[64 * 64];
    __shared__ __align__(16) u16 Vs1[64 * 64];
    __shared__ __align__(16) u16 Pb[4 * 16 * PSTR];

    const int t = threadIdx.x;
    const int lane = t & 63, wave = t >> 6;
    const int l15 = lane & 15, quad = lane >> 4;

    // bijective XCD-chunk swizzle: 1920 blocks = 8 XCDs x 240 contiguous
    const int bid = blockIdx.x;
    const int swz = (bid & 7) * 240 + (bid >> 3);
    const int bh = swz / 10, qt = swz - bh * 10;     // 10 q-tiles per bh
    const int b = bh / 12, h = bh - b * 12;
    const u16* baseQ = qkv + (size_t)b * 577 * 1536 + h * 64;
    const u16* baseK = baseQ + 768;
    const u16* vbase = VtG + (size_t)bh * 64 * 640;

    const int mq = qt * 64 + wave * 16 + l15;
    const int nq = mq < 577 ? mq : 576;
    bf16x8 aq[2];
    aq[0] = *(const bf16x8*)(baseQ + (size_t)nq * 1536 + quad * 8);
    aq[1] = *(const bf16x8*)(baseQ + (size_t)nq * 1536 + 32 + quad * 8);

    // staging map: chunk g (0..511) -> row g>>3, LDS slot g&7, global slot
    // (g&7)^(row&7). One wave-instr = 8 consecutive rows x 128B full lines.
    const int g0 = t, g1 = t + 256;
    const int r0 = g0 >> 3, r1 = g1 >> 3;
    const int s0 = (g0 & 7) ^ (r0 & 7), s1 = (g1 & 7) ^ (r1 & 7);
    const int o0 = g0 * 8, o1 = g1 * 8;              // u16 units (16B chunks)
    const u16* Kp0 = baseK + (size_t)r0 * 1536 + s0 * 8;   // + kt*64*1536
    const u16* Kp1 = baseK + (size_t)r1 * 1536 + s1 * 8;
    const u16* Vp0 = vbase + (size_t)r0 * 640 + s0 * 8;    // + kt*64
    const u16* Vp1 = vbase + (size_t)r1 * 640 + s1 * 8;
    const u16* K9p0 = baseK + (size_t)576 * 1536 + s0 * 8; // kt=9: all rows
    const u16* K9p1 = baseK + (size_t)576 * 1536 + s1 * 8; // clamp to key 576

    // hoisted XOR'd k-granule offsets (row%8 == l15%8 on every read row)
    const int swk0 = (quad ^ (l15 & 7)) * 8;
    const int swk1 = ((4 + quad) ^ (l15 & 7)) * 8;

    u16* Pw = Pb + wave * 16 * PSTR;

    f32x4 oacc[4];
    const f32x4 fz = {0.f, 0.f, 0.f, 0.f};
#pragma unroll
    for (int i = 0; i < 4; ++i) oacc[i] = fz;
    float m4[4] = {-1e30f, -1e30f, -1e30f, -1e30f};
    float l4[4] = {0.f, 0.f, 0.f, 0.f};

#define ASTAGE(kt_, Kd, Vd) do {                                            \
        gld16(Kp0 + (size_t)(kt_) * 98304, (Kd) + o0);                      \
        gld16(Kp1 + (size_t)(kt_) * 98304, (Kd) + o1);                      \
        gld16(Vp0 + (kt_) * 64, (Vd) + o0);                                 \
        gld16(Vp1 + (kt_) * 64, (Vd) + o1);                                 \
    } while (0)

#define ASTAGE9(Kd, Vd) do {                                                \
        gld16(K9p0, (Kd) + o0);                                             \
        gld16(K9p1, (Kd) + o1);                                             \
        gld16(Vp0 + 576, (Vd) + o0);                                        \
        gld16(Vp1 + 576, (Vd) + o1);                                        \
    } while (0)

#define ATT_TILE(kt_, Kb, Vb, MASKED) do {                                  \
        f32x4 sacc[4];                                                      \
        _Pragma("unroll")                                                   \
        for (int nt = 0; nt < 4; ++nt) {                                    \
            sacc[nt] = fz;                                                  \
            const bf16x8 bk0 = *(const bf16x8*)((Kb) + (nt * 16 + l15) * 64 + swk0); \
            sacc[nt] = MFMA16(aq[0], bk0, sacc[nt]);                        \
            const bf16x8 bk1 = *(const bf16x8*)((Kb) + (nt * 16 + l15) * 64 + swk1); \
            sacc[nt] = MFMA16(aq[1], bk1, sacc[nt]);                        \
        }                                                                   \
        float sv[4][4];                                                     \
        _Pragma("unroll")                                                   \
        for (int nt = 0; nt < 4; ++nt)                                      \
            _Pragma("unroll")                                               \
            for (int r = 0; r < 4; ++r) {                                   \
                float s_ = sacc[nt][r];                                     \
                if (MASKED && ((kt_) * 64 + nt * 16 + l15 > 576)) s_ = -1e30f; \
                sv[nt][r] = s_;                                             \
            }                                                               \
        float mt[4];                                                        \
        _Pragma("unroll")                                                   \
        for (int r = 0; r < 4; ++r) {                                       \
            mt[r] = fmaxf(fmaxf(sv[0][r], sv[1][r]), fmaxf(sv[2][r], sv[3][r])); \
            _Pragma("unroll")                                               \
            for (int off = 1; off <= 8; off <<= 1)                          \
                mt[r] = fmaxf(mt[r], __shfl_xor(mt[r], off));               \
        }                                                                   \
        float alpha[4], nmc[4];                                             \
        _Pragma("unroll")                                                   \
        for (int r = 0; r < 4; ++r) {                                       \
            const float mnew = fmaxf(m4[r], mt[r]);                         \
            alpha[r] = exp2_fast((m4[r] - mnew) * CEXP);                    \
            m4[r] = mnew;                                                   \
            nmc[r] = -mnew * CEXP;                                          \
        }                                                                   \
        float lsum[4] = {0.f, 0.f, 0.f, 0.f};                               \
        _Pragma("unroll")                                                   \
        for (int nt = 0; nt < 4; ++nt)                                      \
            _Pragma("unroll")                                               \
            for (int r = 0; r < 4; ++r) {                                   \
                const float p = exp2_fast(__builtin_fmaf(sv[nt][r], CEXP, nmc[r])); \
                lsum[r] += p;                                               \
                Pw[(quad * 4 + r) * PSTR + nt * 16 + l15] = f2b(p);         \
            }                                                               \
        _Pragma("unroll")                                                   \
        for (int r = 0; r < 4; ++r) {                                       \
            _Pragma("unroll")                                               \
            for (int off = 1; off <= 8; off <<= 1)                          \
                lsum[r] += __shfl_xor(lsum[r], off);                        \
            l4[r] = l4[r] * alpha[r] + lsum[r];                             \
        }                                                                   \
        _Pragma("unroll")                                                   \
        for (int dt = 0; dt < 4; ++dt)                                      \
            _Pragma("unroll")                                               \
            for (int r = 0; r < 4; ++r) oacc[dt][r] *= alpha[r];            \
        __asm__ __volatile__("s_waitcnt lgkmcnt(0)" ::: "memory");          \
        _Pragma("unroll")                                                   \
        for (int kc = 0; kc < 2; ++kc) {                                    \
            const bf16x8 pf = *(const bf16x8*)(Pw + l15 * PSTR + kc * 32 + quad * 8); \
            const int swkv = kc ? swk1 : swk0;                              \
            _Pragma("unroll")                                               \
            for (int dt = 0; dt < 4; ++dt) {                                \
                const bf16x8 vf = *(const bf16x8*)((Vb) + (dt * 16 + l15) * 64 + swkv); \
                oacc[dt] = MFMA16(pf, vf, oacc[dt]);                        \
            }                                                               \
        }                                                                   \
    } while (0)

    ASTAGE(0, Ks0, Vs0);
    __syncthreads();                      // drain prologue stage

    for (int kt2 = 0; kt2 < 8; kt2 += 2) {
        ASTAGE(kt2 + 1, Ks1, Vs1);        // prefetch odd tile -> buf1
        ATT_TILE(kt2, Ks0, Vs0, false);
        __syncthreads();
        ASTAGE(kt2 + 2, Ks0, Vs0);        // prefetch even tile -> buf0
        ATT_TILE(kt2 + 1, Ks1, Vs1, false);
        __syncthreads();
    }
    // kt=8 (buf0, staged in last loop iter); prefetch kt=9 tail -> buf1
    ASTAGE9(Ks1, Vs1);
    ATT_TILE(8, Ks0, Vs0, false);
    __syncthreads();
    ATT_TILE(9, Ks1, Vs1, true);          // only tile with invalid keys

#undef ASTAGE
#undef ASTAGE9
#undef ATT_TILE

    float linv[4];
#pragma unroll
    for (int r = 0; r < 4; ++r) linv[r] = 1.f / l4[r];
#pragma unroll
    for (int r = 0; r < 4; ++r) {
        const int n = qt * 64 + wave * 16 + quad * 4 + r;
        if (n < 577) {
            u16* op = aout + ((size_t)b * 577 + n) * 768 + h * 64 + l15;
#pragma unroll
            for (int dt = 0; dt < 4; ++dt)
                op[dt * 16] = f2b(oacc[dt][r] * linv[r]);
        }
    }
}

// ---------------------------------------------------------------------------
// Workspace layout (62,988,288 B total):
//   xb/aout @ 0        (14,180,352)  [xb dead after gemm1; aout overlaps]
//   wqkvT  @ 14,180,352 ( 3,538,944)
//   wprojT @ 17,719,296 ( 1,179,648)
//   qkv    @ 18,898,944 (28,360,704)  [Q,K only; 1536-stride; RoPE applied]
//   VtG    @ 47,259,648 (15,728,640)  [written by gemm1 epilogue]
// ---------------------------------------------------------------------------
extern "C" void kernel_launch(void* const* d_in, const int* in_sizes, int n_in,
                              void* d_out, int out_size, void* d_ws, size_t ws_size,
                              hipStream_t stream) {
    const float* x      = (const float*)d_in[0];
    const float* cosp   = (const float*)d_in[1];
    const float* sinp   = (const float*)d_in[2];
    const float* w_qkv  = (const float*)d_in[3];
    const float* b_qkv  = (const float*)d_in[4];
    const float* w_proj = (const float*)d_in[5];
    const float* b_proj = (const float*)d_in[6];
    float* out = (float*)d_out;

    char* ws = (char*)d_ws;
    u16* xb     = (u16*)(ws);
    u16* aout   = (u16*)(ws);              // overlaps xb (dead after gemm1)
    u16* wqkvT  = (u16*)(ws + 14180352);
    u16* wprojT = (u16*)(ws + 17719296);
    u16* qkv    = (u16*)(ws + 18898944);
    u16* VtG    = (u16*)(ws + 47259648);

    f32_to_bf16<<<6924, 256, 0, stream>>>(x, xb, 7090176);
    transpose_w<<<dim3(96, 24), 256, 0, stream>>>(w_qkv, w_proj, wqkvT, wprojT);
    gemm_bt<2><<<dim3(73, 18), 512, 0, stream>>>(xb, wqkvT, b_qkv, qkv,
                                                 cosp, sinp, VtG, 9232, 2304, 768);
    attn2<<<dim3(1920), 256, 0, stream>>>(qkv, VtG, aout);
    gemm_bt<1><<<dim3(73, 6), 512, 0, stream>>>(aout, wprojT, b_proj, out,
                                                nullptr, nullptr, nullptr, 9232, 768, 768);
}

// Round 4
// 218.000 us; speedup vs baseline: 1.3211x; 1.0531x over previous
//
#include <hip/hip_runtime.h>
#include <stdint.h>

typedef unsigned short u16;
typedef __attribute__((ext_vector_type(8))) short bf16x8;
typedef __attribute__((ext_vector_type(4))) float f32x4;

#define MFMA16(a, b, c) __builtin_amdgcn_mfma_f32_16x16x32_bf16((a), (b), (c), 0, 0, 0)

__device__ __forceinline__ float b2f(u16 u) {
    union { unsigned int i; float f; } v; v.i = ((unsigned int)u) << 16; return v.f;
}
__device__ __forceinline__ u16 f2b(float f) {
    union { float f; unsigned int i; } v; v.f = f;
    unsigned int r = v.i + 0x7fffu + ((v.i >> 16) & 1u);
    return (u16)(r >> 16);
}
// native 2^x (v_exp_f32); schedulable asm, no memory clobber
__device__ __forceinline__ float exp2_fast(float x) {
    float r; __asm__("v_exp_f32 %0, %1" : "=v"(r) : "v"(x)); return r;
}

typedef __attribute__((address_space(1))) void gvoid;
typedef __attribute__((address_space(3))) void lvoid;
__device__ __forceinline__ void gld16(const void* g, void* l) {
    __builtin_amdgcn_global_load_lds((gvoid*)(void*)g, (lvoid*)l, 16, 0, 0);
}

// Panel-swizzled block mapping: 8-row-tile panels, col-major inside a panel.
// Keeps A's reuse window ~1.6 MB -> L2-resident (FETCH 139->52 MB, measured R5).
__device__ __forceinline__ void tile_from_bid(int bid, int nTM, int nTN,
                                              int& rt, int& ct) {
    const int PW = 8;
    const int full = nTM / PW;
    const int per = PW * nTN;
    int p = bid / per;
    int pw = PW;
    int rem = bid - p * per;
    if (p >= full) { p = full; rem = bid - full * per; pw = nTM - full * PW; }
    const int c = rem / pw;
    const int r = rem - c * pw;
    rt = p * PW + r;
    ct = c;
}

// ---------------------------------------------------------------------------
// fp32 -> bf16 elementwise convert (n multiple of 4)
// ---------------------------------------------------------------------------
__global__ __launch_bounds__(256) void f32_to_bf16(const float* __restrict__ in,
                                                   u16* __restrict__ out, int n) {
    const int i = (blockIdx.x * 256 + threadIdx.x) * 4;
    if (i + 3 < n) {
        const float4 v = *(const float4*)(in + i);
        ushort4 o;
        o.x = f2b(v.x); o.y = f2b(v.y); o.z = f2b(v.z); o.w = f2b(v.w);
        *(ushort4*)(out + i) = o;
    }
}

// ---------------------------------------------------------------------------
// merged transpose + fp32->bf16 for BOTH weights (one launch):
//   blockIdx.x <  72: w_qkv (768 x 2304) -> wqkvT (2304 x 768)
//   blockIdx.x >= 72: w_proj (768 x 768) -> wprojT (768 x 768)
// ---------------------------------------------------------------------------
__global__ __launch_bounds__(256) void transpose_w(const float* __restrict__ wqkv,
                                                   const float* __restrict__ wproj,
                                                   u16* __restrict__ outQ,
                                                   u16* __restrict__ outP) {
    __shared__ float tile[32][33];
    int bx = blockIdx.x;
    const float* in; u16* out; int C;
    if (bx < 72) { in = wqkv; out = outQ; C = 2304; }
    else         { bx -= 72; in = wproj; out = outP; C = 768; }
    const int R = 768;
    const int t = threadIdx.x;
    const int r = t >> 3, c4 = (t & 7) * 4;
    const int ir = blockIdx.y * 32 + r, ic = bx * 32 + c4;
    const float4 v = *(const float4*)(in + (size_t)ir * C + ic);
    tile[r][c4 + 0] = v.x; tile[r][c4 + 1] = v.y;
    tile[r][c4 + 2] = v.z; tile[r][c4 + 3] = v.w;
    __syncthreads();
    const int orow = bx * 32 + r, ocol = blockIdx.y * 32 + c4;
    ushort4 o;
    o.x = f2b(tile[c4 + 0][r]); o.y = f2b(tile[c4 + 1][r]);
    o.z = f2b(tile[c4 + 2][r]); o.w = f2b(tile[c4 + 3][r]);
    *(ushort4*)(out + (size_t)orow * R + ocol) = o;
}

// ---------------------------------------------------------------------------
// C = A(bf16)[M x K] * Bt(bf16)[N x K]^T + bias(f32)[N]
// 128x128 tile, BK=64, 512 threads = 8 waves in 2x4 (each wave 64x32:
// acc[4][2] = 32 AGPRs). Double-buffered LDS, one barrier per K-step.
// R10 (kept, verified): coalesced staging (8 rows x 128B full lines per
// wave-instr) + XOR involution on both sides; SQ_LDS_BANK_CONFLICT == 0.
// MFMA operands swapped (D^T: l15 = row, quad*4+r = 4 cols).
// EPI: 1 = f32 store (stride N);
//      2 = fused qkv epilogue (block-uniform branch on col0):
//          Q/K tiles: bias + RoPE (intra-lane pairs) -> qkv (stride 1536);
//          V tiles: bias -> stores contiguous along l15 into VtG[bh][d][n].
// ---------------------------------------------------------------------------
template <int EPI>
__global__ __launch_bounds__(512) void gemm_bt(const u16* __restrict__ A,
                                               const u16* __restrict__ Bt,
                                               const float* __restrict__ bias,
                                               void* __restrict__ Cv,
                                               const float* __restrict__ cosp,
                                               const float* __restrict__ sinp,
                                               u16* __restrict__ VtG,
                                               int M, int N, int K) {
    __shared__ __align__(16) u16 As0[128 * 64];
    __shared__ __align__(16) u16 As1[128 * 64];
    __shared__ __align__(16) u16 Bs0[128 * 64];
    __shared__ __align__(16) u16 Bs1[128 * 64];

    const int t = threadIdx.x;
    const int lane = t & 63;
    const int wave = t >> 6;              // 0..7
    const int l15 = lane & 15, quad = lane >> 4;
    const int wm = wave >> 2;             // 0..1 (64 rows each)
    const int wn = wave & 3;              // 0..3 (32 cols each)

    int rt, ct;
    tile_from_bid(blockIdx.y * gridDim.x + blockIdx.x, gridDim.x, gridDim.y, rt, ct);
    const int row0 = rt * 128;
    const int col0 = ct * 128;

    const f32x4 fz = {0.f, 0.f, 0.f, 0.f};
    f32x4 acc[4][2];
#pragma unroll
    for (int i = 0; i < 4; ++i)
#pragma unroll
        for (int j = 0; j < 2; ++j) acc[i][j] = fz;

    // Coalesced staging map: chunk g -> row g>>3, LDS slot g&7,
    // global slot (g&7)^(row&7) (XOR source pre-swizzle; involution).
    const u16* Ap[2];
    const u16* Bp[2];
    int off[2];
#pragma unroll
    for (int n = 0; n < 2; ++n) {
        const int g = t + n * 512;
        const int row = g >> 3;
        const int slot = (g & 7) ^ (row & 7);
        int ar = row0 + row; if (ar > M - 1) ar = M - 1;   // clamp partial M tile
        Ap[n] = A + (size_t)ar * K + slot * 8;
        Bp[n] = Bt + (size_t)(col0 + row) * K + slot * 8;  // N % 128 == 0
        off[n] = g * 8;                                    // u16 units (linear LDS)
    }

#define STAGE(kt_, Ad, Bd) do {                                            \
        const int kb_ = (kt_) << 6;                                        \
        gld16(Ap[0] + kb_, (Ad) + off[0]);                                 \
        gld16(Ap[1] + kb_, (Ad) + off[1]);                                 \
        gld16(Bp[0] + kb_, (Bd) + off[0]);                                 \
        gld16(Bp[1] + kb_, (Bd) + off[1]);                                 \
    } while (0)

    // Row-major [row][64] LDS; k-granule XOR-swizzled by l15&7.
#define COMPUTE(Asb, Bsb) do {                                             \
        _Pragma("unroll")                                                  \
        for (int kk = 0; kk < 2; ++kk) {                                   \
            const int swk = ((kk * 4 + quad) ^ (l15 & 7)) * 8;             \
            bf16x8 af[4], bfr[2];                                          \
            _Pragma("unroll")                                              \
            for (int mi = 0; mi < 4; ++mi)                                 \
                af[mi] = *(const bf16x8*)((Asb) +                          \
                    ((wm * 4 + mi) * 16 + l15) * 64 + swk);                \
            _Pragma("unroll")                                              \
            for (int ni = 0; ni < 2; ++ni)                                 \
                bfr[ni] = *(const bf16x8*)((Bsb) +                         \
                    ((wn * 2 + ni) * 16 + l15) * 64 + swk);                \
            _Pragma("unroll")                                              \
            for (int mi = 0; mi < 4; ++mi)                                 \
                _Pragma("unroll")                                          \
                for (int ni = 0; ni < 2; ++ni)                             \
                    acc[mi][ni] = MFMA16(bfr[ni], af[mi], acc[mi][ni]);    \
        }                                                                  \
    } while (0)

    const int nKT = K >> 6;               // even (K % 128 == 0)
    STAGE(0, As0, Bs0);                   // prologue: tile 0 -> buf0
    __syncthreads();                      // (drains vmcnt0)

    for (int kt = 0; kt < nKT; kt += 2) {
        if (kt + 1 < nKT) STAGE(kt + 1, As1, Bs1);   // prefetch next -> buf1
        COMPUTE(As0, Bs0);                           // compute current (buf0)
        __syncthreads();                             // buf1 ready; buf0 released
        if (kt + 2 < nKT) STAGE(kt + 2, As0, Bs0);   // prefetch next -> buf0
        COMPUTE(As1, Bs1);                           // compute current (buf1)
        __syncthreads();                             // buf0 ready; buf1 released
    }
#undef STAGE
#undef COMPUTE

    // ---- epilogue (D^T layout: row = ...+l15, cols = colb..colb+3) ----
    if (EPI == 2) {
        if (col0 >= 1536) {
            // V tiles -> VtG[bh][d][n], stores contiguous along l15 (token n)
#pragma unroll
            for (int mi = 0; mi < 4; ++mi) {
                const int row = row0 + wm * 64 + mi * 16 + l15;
                if (row < M) {
                    const int bb = row / 577, n = row - bb * 577;
                    u16* vdst = VtG + (size_t)bb * 491520 + n;   // 12*64*640
#pragma unroll
                    for (int ni = 0; ni < 2; ++ni) {
                        const int colb = col0 + wn * 32 + ni * 16 + quad * 4;
                        const float4 bv = *(const float4*)(bias + colb);
#pragma unroll
                        for (int r = 0; r < 4; ++r) {
                            const int cv = colb + r - 1536;
                            vdst[(size_t)(cv >> 6) * 40960 + (cv & 63) * 640] =
                                f2b(acc[mi][ni][r] + ((const float*)&bv)[r]);
                        }
                    }
                }
            }
        } else {
            // Q/K tiles: bias + RoPE (intra-lane pairs) -> 1536-stride qkv
#pragma unroll
            for (int mi = 0; mi < 4; ++mi) {
                const int row = row0 + wm * 64 + mi * 16 + l15;
                if (row < M) {
                    const int bb = row / 577, n = row - bb * 577;
                    const bool hr = (n >= 1);
                    const float* cb = cosp + (size_t)(hr ? (n - 1) : 0) * 32;
                    const float* sb = sinp + (size_t)(hr ? (n - 1) : 0) * 32;
                    u16* outp = (u16*)Cv + (size_t)row * 1536;
#pragma unroll
                    for (int ni = 0; ni < 2; ++ni) {
                        const int colb = col0 + wn * 32 + ni * 16 + quad * 4;
                        const float4 bv = *(const float4*)(bias + colb);
                        const int pi = (colb & 63) >> 1;           // even
                        float2 c = *(const float2*)(cb + pi);
                        float2 s = *(const float2*)(sb + pi);
                        if (!hr) { c.x = 1.f; c.y = 1.f; s.x = 0.f; s.y = 0.f; }
                        const float v0 = acc[mi][ni][0] + bv.x;
                        const float v1 = acc[mi][ni][1] + bv.y;
                        const float v2 = acc[mi][ni][2] + bv.z;
                        const float v3 = acc[mi][ni][3] + bv.w;
                        ushort4 o;
                        o.x = f2b(v0 * c.x - v1 * s.x);
                        o.y = f2b(v0 * s.x + v1 * c.x);
                        o.z = f2b(v2 * c.y - v3 * s.y);
                        o.w = f2b(v2 * s.y + v3 * c.y);
                        *(ushort4*)(outp + colb) = o;
                    }
                }
            }
        }
    } else {
#pragma unroll
        for (int ni = 0; ni < 2; ++ni) {
            const int colb = col0 + wn * 32 + ni * 16 + quad * 4;
            const float4 bv = *(const float4*)(bias + colb);
#pragma unroll
            for (int mi = 0; mi < 4; ++mi) {
                const int row = row0 + wm * 64 + mi * 16 + l15;
                if (row < M) {
                    float4 o;
                    o.x = acc[mi][ni][0] + bv.x; o.y = acc[mi][ni][1] + bv.y;
                    o.z = acc[mi][ni][2] + bv.z; o.w = acc[mi][ni][3] + bv.w;
                    *(float4*)((float*)Cv + (size_t)row * N + colb) = o;
                }
            }
        }
    }
}

// ---------------------------------------------------------------------------
// Flash attention R12: SWAPPED-OPERAND layout (reduction axis lane-local).
// QK^T computes MFMA16(bk, aq) -> D: col=l15=QUERY, row=quad*4+r=KEY.
// Each lane owns ONE query and 16 key-scores in registers -> max/sum are
// in-register trees + only 2 shfl_xor rounds (quad axis: 16,32) instead of
// 4+4 dependent bpermute rounds (R3 showed the serial shfl chain was the
// invariant critical path: all pipes <40% while dur stuck at 88us).
// m/l/alpha are per-lane scalars; oacc rescale is scalar; P-writes are 4x
// ds_write_b64 (was 16x b16 -> the constant 614400 bank-conflict term);
// lsum cross-quad reduce deferred PAST the PV MFMAs (latency overlap).
// PV computes MFMA16(vf, pf) -> D: col=l15=query, row=quad*4+r=d ->
// final store packs ushort4 (d = dt*16+quad*4+r consecutive in r).
// Grid: bijective XCD-chunk swizzle (FETCH 124->21.6MB, verified R3).
// Double-buffered K/V staging, coalesced + XOR involution (verified R2).
// ---------------------------------------------------------------------------
#define PSTR 72
#define CEXP 0.18033688011112042f   /* 0.125 * log2(e) */

__global__ __launch_bounds__(256) void attn2(const u16* __restrict__ qkv,
                                             const u16* __restrict__ VtG,
                                             u16* __restrict__ aout) {
    __shared__ __align__(16) u16 Ks0[64 * 64];
    __shared__ __align__(16) u16 Ks1[64 * 64];
    __shared__ __align__(16) u16 Vs0[64 * 64];
    __shared__ __align__(16) u16 Vs1[64 * 64];
    __shared__ __align__(16) u16 Pb[4 * 16 * PSTR];

    const int t = threadIdx.x;
    const int lane = t & 63, wave = t >> 6;
    const int l15 = lane & 15, quad = lane >> 4;

    // bijective XCD-chunk swizzle: 1920 blocks = 8 XCDs x 240 contiguous
    const int bid = blockIdx.x;
    const int swz = (bid & 7) * 240 + (bid >> 3);
    const int bh = swz / 10, qt = swz - bh * 10;     // 10 q-tiles per bh
    const int b = bh / 12, h = bh - b * 12;
    const u16* baseQ = qkv + (size_t)b * 577 * 1536 + h * 64;
    const u16* baseK = baseQ + 768;
    const u16* vbase = VtG + (size_t)bh * 64 * 640;

    const int mq = qt * 64 + wave * 16 + l15;        // this lane's query
    const int nq = mq < 577 ? mq : 576;
    bf16x8 aq[2];
    aq[0] = *(const bf16x8*)(baseQ + (size_t)nq * 1536 + quad * 8);
    aq[1] = *(const bf16x8*)(baseQ + (size_t)nq * 1536 + 32 + quad * 8);

    // staging map: chunk g (0..511) -> row g>>3, LDS slot g&7, global slot
    // (g&7)^(row&7). One wave-instr = 8 consecutive rows x 128B full lines.
    const int g0 = t, g1 = t + 256;
    const int r0 = g0 >> 3, r1 = g1 >> 3;
    const int s0 = (g0 & 7) ^ (r0 & 7), s1 = (g1 & 7) ^ (r1 & 7);
    const int o0 = g0 * 8, o1 = g1 * 8;              // u16 units (16B chunks)
    const u16* Kp0 = baseK + (size_t)r0 * 1536 + s0 * 8;   // + kt*64*1536
    const u16* Kp1 = baseK + (size_t)r1 * 1536 + s1 * 8;
    const u16* Vp0 = vbase + (size_t)r0 * 640 + s0 * 8;    // + kt*64
    const u16* Vp1 = vbase + (size_t)r1 * 640 + s1 * 8;
    const u16* K9p0 = baseK + (size_t)576 * 1536 + s0 * 8; // kt=9: all rows
    const u16* K9p1 = baseK + (size_t)576 * 1536 + s1 * 8; // clamp to key 576

    // hoisted XOR'd k-granule offsets (row%8 == l15%8 on every read row)
    const int swk0 = (quad ^ (l15 & 7)) * 8;
    const int swk1 = ((4 + quad) ^ (l15 & 7)) * 8;

    u16* Pw = Pb + wave * 16 * PSTR;

    f32x4 oacc[4];
    const f32x4 fz = {0.f, 0.f, 0.f, 0.f};
#pragma unroll
    for (int i = 0; i < 4; ++i) oacc[i] = fz;
    float m1 = -1e30f;
    float l1 = 0.f;

#define ASTAGE(kt_, Kd, Vd) do {                                            \
        gld16(Kp0 + (size_t)(kt_) * 98304, (Kd) + o0);                      \
        gld16(Kp1 + (size_t)(kt_) * 98304, (Kd) + o1);                      \
        gld16(Vp0 + (kt_) * 64, (Vd) + o0);                                 \
        gld16(Vp1 + (kt_) * 64, (Vd) + o1);                                 \
    } while (0)

#define ASTAGE9(Kd, Vd) do {                                                \
        gld16(K9p0, (Kd) + o0);                                             \
        gld16(K9p1, (Kd) + o1);                                             \
        gld16(Vp0 + 576, (Vd) + o0);                                        \
        gld16(Vp1 + 576, (Vd) + o1);                                        \
    } while (0)

#define ATT_TILE(kt_, Kb, Vb, MASKED) do {                                  \
        f32x4 sacc[4];                                                      \
        _Pragma("unroll")                                                   \
        for (int nt = 0; nt < 4; ++nt) {                                    \
            sacc[nt] = fz;                                                  \
            const bf16x8 bk0 = *(const bf16x8*)((Kb) + (nt * 16 + l15) * 64 + swk0); \
            sacc[nt] = MFMA16(bk0, aq[0], sacc[nt]);                        \
            const bf16x8 bk1 = *(const bf16x8*)((Kb) + (nt * 16 + l15) * 64 + swk1); \
            sacc[nt] = MFMA16(bk1, aq[1], sacc[nt]);                        \
        }                                                                   \
        if (MASKED) {                                                       \
            _Pragma("unroll")                                               \
            for (int nt = 0; nt < 4; ++nt)                                  \
                _Pragma("unroll")                                           \
                for (int r = 0; r < 4; ++r)                                 \
                    if (nt * 16 + quad * 4 + r > 0) sacc[nt][r] = -1e30f;   \
        }                                                                   \
        float mA = fmaxf(fmaxf(sacc[0][0], sacc[0][1]), fmaxf(sacc[0][2], sacc[0][3])); \
        float mB = fmaxf(fmaxf(sacc[1][0], sacc[1][1]), fmaxf(sacc[1][2], sacc[1][3])); \
        float mC = fmaxf(fmaxf(sacc[2][0], sacc[2][1]), fmaxf(sacc[2][2], sacc[2][3])); \
        float mD = fmaxf(fmaxf(sacc[3][0], sacc[3][1]), fmaxf(sacc[3][2], sacc[3][3])); \
        float mt = fmaxf(fmaxf(mA, mB), fmaxf(mC, mD));                     \
        mt = fmaxf(mt, __shfl_xor(mt, 16));                                 \
        mt = fmaxf(mt, __shfl_xor(mt, 32));                                 \
        const float mnew = fmaxf(m1, mt);                                   \
        const float alpha = exp2_fast((m1 - mnew) * CEXP);                  \
        m1 = mnew;                                                          \
        const float nmc = -mnew * CEXP;                                     \
        float lsum = 0.f;                                                   \
        _Pragma("unroll")                                                   \
        for (int nt = 0; nt < 4; ++nt) {                                    \
            const float p0 = exp2_fast(__builtin_fmaf(sacc[nt][0], CEXP, nmc)); \
            const float p1 = exp2_fast(__builtin_fmaf(sacc[nt][1], CEXP, nmc)); \
            const float p2 = exp2_fast(__builtin_fmaf(sacc[nt][2], CEXP, nmc)); \
            const float p3 = exp2_fast(__builtin_fmaf(sacc[nt][3], CEXP, nmc)); \
            lsum += (p0 + p1) + (p2 + p3);                                  \
            ushort4 pk;                                                     \
            pk.x = f2b(p0); pk.y = f2b(p1); pk.z = f2b(p2); pk.w = f2b(p3); \
            *(ushort4*)(Pw + l15 * PSTR + nt * 16 + quad * 4) = pk;         \
        }                                                                   \
        _Pragma("unroll")                                                   \
        for (int dt = 0; dt < 4; ++dt) {                                    \
            oacc[dt][0] *= alpha; oacc[dt][1] *= alpha;                     \
            oacc[dt][2] *= alpha; oacc[dt][3] *= alpha;                     \
        }                                                                   \
        __asm__ __volatile__("s_waitcnt lgkmcnt(0)" ::: "memory");          \
        _Pragma("unroll")                                                   \
        for (int kc = 0; kc < 2; ++kc) {                                    \
            const bf16x8 pf = *(const bf16x8*)(Pw + l15 * PSTR + kc * 32 + quad * 8); \
            const int swkv = kc ? swk1 : swk0;                              \
            _Pragma("unroll")                                               \
            for (int dt = 0; dt < 4; ++dt) {                                \
                const bf16x8 vf = *(const bf16x8*)((Vb) + (dt * 16 + l15) * 64 + swkv); \
                oacc[dt] = MFMA16(vf, pf, oacc[dt]);                        \
            }                                                               \
        }                                                                   \
        lsum += __shfl_xor(lsum, 16);                                       \
        lsum += __shfl_xor(lsum, 32);                                       \
        l1 = l1 * alpha + lsum;                                             \
    } while (0)

    ASTAGE(0, Ks0, Vs0);
    __syncthreads();                      // drain prologue stage

    for (int kt2 = 0; kt2 < 8; kt2 += 2) {
        ASTAGE(kt2 + 1, Ks1, Vs1);        // prefetch odd tile -> buf1
        ATT_TILE(kt2, Ks0, Vs0, false);
        __syncthreads();
        ASTAGE(kt2 + 2, Ks0, Vs0);        // prefetch even tile -> buf0
        ATT_TILE(kt2 + 1, Ks1, Vs1, false);
        __syncthreads();
    }
    // kt=8 (buf0, staged in last loop iter); prefetch kt=9 tail -> buf1
    ASTAGE9(Ks1, Vs1);
    ATT_TILE(8, Ks0, Vs0, false);
    __syncthreads();
    ATT_TILE(9, Ks1, Vs1, true);          // only tile with invalid keys

#undef ASTAGE
#undef ASTAGE9
#undef ATT_TILE

    // final: lane owns query l15; d = dt*16 + quad*4 + r (packed ushort4)
    const int n = qt * 64 + wave * 16 + l15;
    if (n < 577) {
        const float linv = 1.f / l1;
        u16* op = aout + ((size_t)b * 577 + n) * 768 + h * 64 + quad * 4;
#pragma unroll
        for (int dt = 0; dt < 4; ++dt) {
            ushort4 o;
            o.x = f2b(oacc[dt][0] * linv); o.y = f2b(oacc[dt][1] * linv);
            o.z = f2b(oacc[dt][2] * linv); o.w = f2b(oacc[dt][3] * linv);
            *(ushort4*)(op + dt * 16) = o;
        }
    }
}

// ---------------------------------------------------------------------------
// Workspace layout (62,988,288 B total):
//   xb/aout @ 0        (14,180,352)  [xb dead after gemm1; aout overlaps]
//   wqkvT  @ 14,180,352 ( 3,538,944)
//   wprojT @ 17,719,296 ( 1,179,648)
//   qkv    @ 18,898,944 (28,360,704)  [Q,K only; 1536-stride; RoPE applied]
//   VtG    @ 47,259,648 (15,728,640)  [written by gemm1 epilogue]
// ---------------------------------------------------------------------------
extern "C" void kernel_launch(void* const* d_in, const int* in_sizes, int n_in,
                              void* d_out, int out_size, void* d_ws, size_t ws_size,
                              hipStream_t stream) {
    const float* x      = (const float*)d_in[0];
    const float* cosp   = (const float*)d_in[1];
    const float* sinp   = (const float*)d_in[2];
    const float* w_qkv  = (const float*)d_in[3];
    const float* b_qkv  = (const float*)d_in[4];
    const float* w_proj = (const float*)d_in[5];
    const float* b_proj = (const float*)d_in[6];
    float* out = (float*)d_out;

    char* ws = (char*)d_ws;
    u16* xb     = (u16*)(ws);
    u16* aout   = (u16*)(ws);              // overlaps xb (dead after gemm1)
    u16* wqkvT  = (u16*)(ws + 14180352);
    u16* wprojT = (u16*)(ws + 17719296);
    u16* qkv    = (u16*)(ws + 18898944);
    u16* VtG    = (u16*)(ws + 47259648);

    f32_to_bf16<<<6924, 256, 0, stream>>>(x, xb, 7090176);
    transpose_w<<<dim3(96, 24), 256, 0, stream>>>(w_qkv, w_proj, wqkvT, wprojT);
    gemm_bt<2><<<dim3(73, 18), 512, 0, stream>>>(xb, wqkvT, b_qkv, qkv,
                                                 cosp, sinp, VtG, 9232, 2304, 768);
    attn2<<<dim3(1920), 256, 0, stream>>>(qkv, VtG, aout);
    gemm_bt<1><<<dim3(73, 6), 512, 0, stream>>>(aout, wprojT, b_proj, out,
                                                nullptr, nullptr, nullptr, 9232, 768, 768);
}